// Round 12
// baseline (482.661 us; speedup 1.0000x reference)
//
#include <hip/hip_runtime.h>
#include <hip/hip_bf16.h>
#include <math.h>

#define NN 100000
#define EE 3200000
#define ET (EE + NN)          // edges incl. self loops
#define FIN 1433
#define KPAD 1440
#define NT 45                 // K tiles of 32
#define F1 64
#define F2 7
#define NB 391                // ceil(NN/256)
#define G1B 782               // gemm1 blocks (ceil(NN/BM))
#define SB 1024               // scatter blocks in fuse1
#define CAP 128               // compacted CSR capacity per node
#define NXCD 8
#define CAPX 24               // per-(node,xcd) sublist capacity
#define A1B 3125              // att1 blocks in fuse2
#define CPB 25000             // compact blocks in fuse2 (4 nodes each)

typedef __attribute__((ext_vector_type(8))) short short8;
typedef __attribute__((ext_vector_type(4))) float f32x4;
typedef __attribute__((address_space(3))) unsigned int u32_lds;
typedef __attribute__((address_space(1))) const unsigned int u32_glb;

static __device__ __forceinline__ unsigned short f2bf(float f) {
  __hip_bfloat16 h = __float2bfloat16(f);
  return *reinterpret_cast<unsigned short*>(&h);
}
static __device__ __forceinline__ float bf2f(unsigned short u) {
  return __uint_as_float((unsigned int)u << 16);
}

// ---------------- prep: zero cnt2 + W1^T bf16 (padded) ----------------
__global__ __launch_bounds__(256) void k_prep(const float* __restrict__ W1,
                                              int* __restrict__ cnt2,
                                              unsigned short* __restrict__ WT) {
  int i = blockIdx.x * 256 + threadIdx.x;
  if (i < NXCD * NN) cnt2[i] = 0;
  if (i < F1 * KPAD) {
    int c = i / KPAD, k = i - c * KPAD;
    WT[i] = f2bf((k < FIN) ? W1[k * F1 + c] : 0.f);
  }
}

// ---------------- fuse1: gemm1 (blocks 0..G1B) || per-XCD scatter ----------------
#define BM 128
#define TILEA 16384           // 128 rows x 32 k x f32
#define TILEB 4096            // 64 cols x 32 k x bf16
#define BUFB (TILEA + TILEB)  // 20480

__global__ __launch_bounds__(256) void k_fuse1(const float* __restrict__ X,
                                               const unsigned short* __restrict__ WT,
                                               unsigned short* __restrict__ Hb,
                                               const int* __restrict__ ei,
                                               int* __restrict__ cnt2,
                                               int* __restrict__ csr2) {
  if (blockIdx.x >= G1B) {
    // ---- scatter into per-XCD CSR sublists; cursor atomics stay in local L2 ----
    int xcc;
    asm volatile("s_getreg_b32 %0, hwreg(20, 0, 32)" : "=s"(xcc));  // HW_REG_XCC_ID
    xcc &= 7;
    int* mycnt = cnt2 + xcc * NN;
    int* mycsr = csr2 + (size_t)xcc * NN * CAPX;
    const int stride = SB * 256;
    for (int e = (blockIdx.x - G1B) * 256 + threadIdx.x; e < ET; e += stride) {
      int src, dst;
      if (e < EE) { src = ei[e]; dst = ei[EE + e]; }
      else        { src = e - EE; dst = src; }
      int pos = __hip_atomic_fetch_add(&mycnt[dst], 1, __ATOMIC_RELAXED,
                                       __HIP_MEMORY_SCOPE_WORKGROUP);
      mycsr[dst * CAPX + pos] = src;
    }
    return;
  }
  // ---- gemm1: h1 = x @ W1, bf16 MFMA (global_load_lds staged), output bf16 ----
  __shared__ __align__(16) char smem[2 * BUFB];
  const int tid = threadIdx.x;
  const int lane = tid & 63;
  const int wid = tid >> 6;
  const int row0 = blockIdx.x * BM;
  const int wr = (wid >> 1) * 64;
  const int wc = (wid & 1) * 32;
  const int l15 = lane & 15, l4 = lane >> 4;

  const int lrq = tid >> 3;          // 0..31 (row within 32-row pass)
  const int mq = tid & 7;            // lds 16-B chunk slot
  const char* Xb = (const char*)X;
  size_t aoff[4];
#pragma unroll
  for (int q = 0; q < 4; ++q) {
    int lr = q * 32 + lrq;
    int gr = row0 + lr; if (gr >= NN) gr = NN - 1;
    int c = mq ^ (lr & 7);           // source chunk (inverse swizzle)
    aoff[q] = (size_t)gr * (FIN * 4) + (size_t)c * 16;
  }
  const unsigned short* bsrc =
      WT + (tid >> 2) * KPAD + (((tid & 3) ^ ((tid >> 3) & 3)) << 3);

  f32x4 acc[4][2];
#pragma unroll
  for (int a = 0; a < 4; ++a)
#pragma unroll
    for (int b = 0; b < 2; ++b) acc[a][b] = 0.f;

  auto gstage = [&](int k0, char* buf) {
#pragma unroll
    for (int q = 0; q < 4; ++q) {
      __builtin_amdgcn_global_load_lds(
          (u32_glb*)(Xb + aoff[q] + (size_t)k0 * 4),
          (u32_lds*)(buf + q * 4096 + wid * 1024), 16, 0, 0);
    }
  };

  gstage(0, smem);
  {
    short8 b0 = *(const short8*)(bsrc + 0);
    *(short8*)(smem + TILEA + tid * 16) = b0;
  }
  __syncthreads();

  int cur = 0;
  for (int t = 0; t < NT; ++t) {
    char* buf = smem + cur * BUFB;
    char* nbuf = smem + (cur ^ 1) * BUFB;
    const bool have_next = (t + 1 < NT);
    const bool tail = (t + 1 == NT - 1);
    short8 bnext;
    f32x4 atail[4];
    if (have_next) {
      if (!tail) {
        gstage((t + 1) * 32, nbuf);
      } else {
#pragma unroll
        for (int q = 0; q < 4; ++q) {
          int lr = q * 32 + lrq;
          int gr = row0 + lr; if (gr >= NN) gr = NN - 1;
          int c = mq ^ (lr & 7);
          int kb = (NT - 1) * 32 + c * 4;
          const float* xp = X + (size_t)gr * FIN + kb;
#pragma unroll
          for (int j = 0; j < 4; ++j)
            atail[q][j] = (kb + j < FIN) ? xp[j] : 0.f;
        }
      }
      bnext = *(const short8*)(bsrc + (t + 1) * 32);
    }

    short8 af[4], bf[2];
    const int sz = l15 & 7;
#pragma unroll
    for (int fr = 0; fr < 4; ++fr) {
      int r = wr + fr * 16 + l15;
      f32x4 a0 = *(const f32x4*)(buf + r * 128 + ((2 * l4) ^ sz) * 16);
      f32x4 a1 = *(const f32x4*)(buf + r * 128 + ((2 * l4 + 1) ^ sz) * 16);
      short8 v;
#pragma unroll
      for (int j = 0; j < 4; ++j) {
        v[j] = (short)f2bf(a0[j]);
        v[4 + j] = (short)f2bf(a1[j]);
      }
      af[fr] = v;
    }
#pragma unroll
    for (int fc = 0; fc < 2; ++fc) {
      int c = wc + fc * 16 + l15;
      int jp = l4 ^ ((c >> 1) & 3);
      bf[fc] = *(const short8*)(buf + TILEA + c * 64 + jp * 16);
    }
#pragma unroll
    for (int fr = 0; fr < 4; ++fr)
#pragma unroll
      for (int fc = 0; fc < 2; ++fc)
        acc[fr][fc] = __builtin_amdgcn_mfma_f32_16x16x32_bf16(
            af[fr], bf[fc], acc[fr][fc], 0, 0, 0);

    if (have_next) {
      if (tail) {
#pragma unroll
        for (int q = 0; q < 4; ++q)
          *(f32x4*)(nbuf + (q * 32 + lrq) * 128 + mq * 16) = atail[q];
      }
      *(short8*)(nbuf + TILEA + tid * 16) = bnext;
    }
    __syncthreads();
    cur ^= 1;
  }

#pragma unroll
  for (int fr = 0; fr < 4; ++fr) {
    int rbase = row0 + wr + fr * 16 + l4 * 4;
#pragma unroll
    for (int q = 0; q < 4; ++q) {
      int r = rbase + q;
      if (r < NN) {
#pragma unroll
        for (int fc = 0; fc < 2; ++fc)
          Hb[(size_t)r * F1 + wc + fc * 16 + l15] = f2bf(acc[fr][fc][q]);
      }
    }
  }
}

// ---------------- fuse2: att1 (blocks 0..A1B) || compact csr2 -> csr ----------------
__global__ __launch_bounds__(256) void k_fuse2(const unsigned short* __restrict__ Hb,
                                               const float* __restrict__ attS,
                                               const float* __restrict__ attD,
                                               float* __restrict__ aS,
                                               float* __restrict__ aD,
                                               const int* __restrict__ cnt2,
                                               const int* __restrict__ csr2,
                                               int* __restrict__ cnt,
                                               int* __restrict__ csr) {
  if (blockIdx.x >= A1B) {
    // ---- compact 8 per-XCD sublists into contiguous csr[n*128 ..] ----
    const int wv = threadIdx.x >> 6, lane = threadIdx.x & 63;
    const int n = (blockIdx.x - A1B) * 4 + wv;
    if (n >= NN) return;
    int c[NXCD];
    int deg = 0;
#pragma unroll
    for (int x = 0; x < NXCD; ++x) { c[x] = cnt2[x * NN + n]; deg += c[x]; }
    for (int i = lane; i < deg; i += 64) {
      int x = 0, off = i;
      while (off >= c[x]) { off -= c[x]; ++x; }
      csr[(n << 7) + i] = csr2[((size_t)x * NN + n) * CAPX + off];
    }
    if (lane == 0) cnt[n] = deg;
    return;
  }
  // ---- att1: per-node attention scores (8 threads/node) ----
  __shared__ float s_s[64], s_d[64];
  if (threadIdx.x < 64) { s_s[threadIdx.x] = attS[threadIdx.x]; s_d[threadIdx.x] = attD[threadIdx.x]; }
  __syncthreads();
  int idx = blockIdx.x * 256 + threadIdx.x;
  int n = idx >> 3, h = idx & 7;
  if (n >= NN) return;
  short8 v8 = *(const short8*)(Hb + (size_t)n * 64 + h * 8);
  float ss = 0.f, dd = 0.f;
#pragma unroll
  for (int c = 0; c < 8; ++c) {
    float v = bf2f((unsigned short)v8[c]);
    ss = fmaf(v, s_s[h * 8 + c], ss);
    dd = fmaf(v, s_d[h * 8 + c], dd);
  }
  aS[n * 8 + h] = ss;
  aD[n * 8 + h] = dd;
}

// ---------------- agg1 + fused gemm2/att2: wave per node, 8 edges x 8 heads ----
__global__ __launch_bounds__(256) void k_agg1(const unsigned short* __restrict__ Hb,
                                              const float* __restrict__ aS,
                                              const float* __restrict__ aD,
                                              const int* __restrict__ cnt,
                                              const int* __restrict__ csr,
                                              const float* __restrict__ b1,
                                              const float* __restrict__ W2,
                                              const float* __restrict__ s2,
                                              const float* __restrict__ d2,
                                              unsigned short* __restrict__ H2b,
                                              float* __restrict__ aD2) {
  __shared__ float s_w2[448];
  __shared__ float s_ss[7], s_dd[7];
  __shared__ float s_b1[64];
  for (int i = threadIdx.x; i < 448; i += 256) s_w2[i] = W2[i];
  if (threadIdx.x < 7) { s_ss[threadIdx.x] = s2[threadIdx.x]; s_dd[threadIdx.x] = d2[threadIdx.x]; }
  if (threadIdx.x < 64) s_b1[threadIdx.x] = b1[threadIdx.x];
  __syncthreads();

  const int wv = threadIdx.x >> 6, lane = threadIdx.x & 63;
  const int n = blockIdx.x * 4 + wv;
  if (n >= NN) return;
  const int eg = lane >> 3, q = lane & 7;
  const float adv = aD[n * 8 + q];
  const int beg = n << 7;
  const int deg = cnt[n];
  float acc[8] = {};
  float den = 0.f;
#pragma unroll 2
  for (int i = eg; i < deg; i += 8) {
    int s = csr[beg + i];                 // broadcast within eg-group
    float e = aS[s * 8 + q] + adv;
    e = (e > 0.f) ? e : 0.2f * e;         // leaky_relu
    float w = __expf(e);                  // max-shift unnecessary (|e| bounded)
    den += w;
    short8 hv = *(const short8*)(Hb + (size_t)s * 64 + q * 8);
#pragma unroll
    for (int c = 0; c < 8; ++c)
      acc[c] = fmaf(w, bf2f((unsigned short)hv[c]), acc[c]);
  }
#pragma unroll
  for (int off = 8; off < 64; off <<= 1) {
    den += __shfl_xor(den, off, 64);
#pragma unroll
    for (int c = 0; c < 8; ++c) acc[c] += __shfl_xor(acc[c], off, 64);
  }
  if (eg == 0) {                          // lanes 0..7: lane q holds head q's 8 ch
    float inv = 1.f / den;
    float v[8];
#pragma unroll
    for (int c = 0; c < 8; ++c) {
      float t = acc[c] * inv + s_b1[q * 8 + c];
      v[c] = (t > 0.f) ? t : (__expf(t) - 1.f);   // ELU
    }
    float p[7] = {};
#pragma unroll
    for (int c = 0; c < 8; ++c) {
      const float* wr = &s_w2[(q * 8 + c) * 7];
#pragma unroll
      for (int j = 0; j < 7; ++j) p[j] = fmaf(v[c], wr[j], p[j]);
    }
#pragma unroll
    for (int off = 1; off < 8; off <<= 1) {
#pragma unroll
      for (int j = 0; j < 7; ++j) p[j] += __shfl_xor(p[j], off, 64);
    }
    if (q == 0) {
      float s = 0.f, d = 0.f;
      short8 row;
#pragma unroll
      for (int j = 0; j < 7; ++j) {
        row[j] = (short)f2bf(p[j]);
        s = fmaf(p[j], s_ss[j], s);
        d = fmaf(p[j], s_dd[j], d);
      }
      row[7] = (short)f2bf(s);            // a_src score packed in slot 7
      *(short8*)(H2b + (size_t)n * 8) = row;
      aD2[n] = d;
    }
  }
}

// ---------------- aggregation layer 2: wave per node, lanes split edges ----------------
__global__ __launch_bounds__(256) void k_agg2(const unsigned short* __restrict__ H2b,
                                              const float* __restrict__ aD2,
                                              const int* __restrict__ cnt,
                                              const int* __restrict__ csr,
                                              const float* __restrict__ b2,
                                              float* __restrict__ out) {
  const int wv = threadIdx.x >> 6, lane = threadIdx.x & 63;
  const int n = blockIdx.x * 4 + wv;
  if (n >= NN) return;
  const float adv = aD2[n];
  const int beg = n << 7;
  const int deg = cnt[n];
  float acc[7] = {};
  float den = 0.f;
  for (int j = lane; j < deg; j += 64) {
    int s = csr[beg + j];
    short8 hv = *(const short8*)(H2b + (size_t)s * 8);
    float e = bf2f((unsigned short)hv[7]) + adv;
    e = (e > 0.f) ? e : 0.2f * e;
    float wgt = __expf(e);
    den += wgt;
#pragma unroll
    for (int c = 0; c < 7; ++c)
      acc[c] = fmaf(wgt, bf2f((unsigned short)hv[c]), acc[c]);
  }
#pragma unroll
  for (int off = 32; off > 0; off >>= 1) {
    den += __shfl_xor(den, off, 64);
#pragma unroll
    for (int c = 0; c < 7; ++c) acc[c] += __shfl_xor(acc[c], off, 64);
  }
  if (lane == 0) {
    float inv = 1.f / den;
    float v[7];
    float m = -1e30f;
#pragma unroll
    for (int c = 0; c < 7; ++c) { v[c] = acc[c] * inv + b2[c]; m = fmaxf(m, v[c]); }
    float se = 0.f;
#pragma unroll
    for (int c = 0; c < 7; ++c) se += __expf(v[c] - m);
    float lse = m + __logf(se);
#pragma unroll
    for (int c = 0; c < 7; ++c) out[n * 7 + c] = v[c] - lse;
  }
}

extern "C" void kernel_launch(void* const* d_in, const int* in_sizes, int n_in,
                              void* d_out, int out_size, void* d_ws, size_t ws_size,
                              hipStream_t stream) {
  const float* x   = (const float*)d_in[0];
  const int*   ei  = (const int*)d_in[1];
  const float* W1  = (const float*)d_in[2];
  const float* as1 = (const float*)d_in[3];
  const float* ad1 = (const float*)d_in[4];
  const float* b1  = (const float*)d_in[5];
  const float* W2  = (const float*)d_in[6];
  const float* as2 = (const float*)d_in[7];
  const float* ad2 = (const float*)d_in[8];
  const float* b2  = (const float*)d_in[9];
  float* out = (float*)d_out;

  char* ws = (char*)d_ws;
  size_t off = 0;
  auto alloc = [&](size_t bytes) {
    void* p = ws + off;
    off += (bytes + 255) & ~(size_t)255;
    return p;
  };
  unsigned short* h1b = (unsigned short*)alloc((size_t)NN * 64 * 2);
  float* sc1    = (float*)alloc((size_t)NN * 8 * 4);
  float* dc1    = (float*)alloc((size_t)NN * 8 * 4);
  unsigned short* h2b = (unsigned short*)alloc((size_t)NN * 8 * 2);
  float* dc2    = (float*)alloc((size_t)NN * 4);
  int*   cnt    = (int*)alloc((size_t)NN * 4);
  int*   csr    = (int*)alloc((size_t)NN * CAP * 4);
  int*   cnt2   = (int*)alloc((size_t)NXCD * NN * 4);
  int*   csr2   = (int*)alloc((size_t)NXCD * NN * CAPX * 4);
  unsigned short* w1t = (unsigned short*)alloc((size_t)F1 * KPAD * 2);

  // prep: zero cnt2 + W1^T
  k_prep<<<(NXCD * NN + 255) / 256, 256, 0, stream>>>(W1, cnt2, w1t);

  // gemm1 || per-XCD scatter
  k_fuse1<<<G1B + SB, 256, 0, stream>>>(x, w1t, h1b, ei, cnt2, csr2);

  // att1 || compact
  k_fuse2<<<A1B + CPB, 256, 0, stream>>>(h1b, as1, ad1, sc1, dc1,
                                         cnt2, csr2, cnt, csr);

  // agg1 + fused gemm2/att2
  k_agg1<<<(NN + 3) / 4, 256, 0, stream>>>(h1b, sc1, dc1, cnt, csr, b1,
                                           W2, as2, ad2, h2b, dc2);

  // agg2 + log_softmax
  k_agg2<<<(NN + 3) / 4, 256, 0, stream>>>(h2b, dc2, cnt, csr, b2, out);
}

// Round 13
// 444.562 us; speedup vs baseline: 1.0857x; 1.0857x over previous
//
#include <hip/hip_runtime.h>
#include <hip/hip_bf16.h>
#include <math.h>

#define NN 100000
#define EE 3200000
#define ET (EE + NN)          // edges incl. self loops
#define FIN 1433
#define KPAD 1440
#define NT 45                 // K tiles of 32
#define F1 64
#define F2 7
#define NB 391                // ceil(NN/256)
#define G1B 782               // gemm1 blocks (ceil(NN/BM))
#define SB 832                // scatter blocks in fuse1
#define NE 16                 // edges per scatter thread (batched)
#define CAP 128               // padded CSR capacity per node

typedef __attribute__((ext_vector_type(8))) short short8;
typedef __attribute__((ext_vector_type(4))) float f32x4;
typedef __attribute__((address_space(3))) unsigned int u32_lds;
typedef __attribute__((address_space(1))) const unsigned int u32_glb;

static __device__ __forceinline__ unsigned short f2bf(float f) {
  __hip_bfloat16 h = __float2bfloat16(f);
  return *reinterpret_cast<unsigned short*>(&h);
}
static __device__ __forceinline__ float bf2f(unsigned short u) {
  return __uint_as_float((unsigned int)u << 16);
}

// ---------------- prep: zero cnt + W1^T bf16 (padded) ----------------
__global__ __launch_bounds__(256) void k_prep(const float* __restrict__ W1,
                                              int* __restrict__ cnt,
                                              unsigned short* __restrict__ WT) {
  int i = blockIdx.x * 256 + threadIdx.x;
  if (i < NN) cnt[i] = 0;
  if (i < F1 * KPAD) {
    int c = i / KPAD, k = i - c * KPAD;
    WT[i] = f2bf((k < FIN) ? W1[k * F1 + c] : 0.f);
  }
}

// ---------------- fuse1: gemm1 (blocks 0..G1B) || batched scatter ----------------
#define BM 128
#define TILEA 16384           // 128 rows x 32 k x f32
#define TILEB 4096            // 64 cols x 32 k x bf16
#define BUFB (TILEA + TILEB)  // 20480

__global__ __launch_bounds__(256) void k_fuse1(const float* __restrict__ X,
                                               const unsigned short* __restrict__ WT,
                                               unsigned short* __restrict__ Hb,
                                               const int* __restrict__ ei,
                                               int* __restrict__ cnt,
                                               int* __restrict__ csr) {
  if (blockIdx.x >= G1B) {
    // ---- batched scatter: 16 edges/thread; all loads, then all atomics,
    //      then all stores -> 16 atomics in flight per thread ----
    const int base = (blockIdx.x - G1B) * 256 + threadIdx.x;
    const int stride = SB * 256;
    int src[NE], dst[NE], pos[NE];
#pragma unroll
    for (int j = 0; j < NE; ++j) {
      int e = base + j * stride;
      bool v = (e < ET);
      int ee = v ? e : 0;
      int d = (ee < EE) ? ei[EE + ee] : (ee - EE);
      int s = (ee < EE) ? ei[ee] : d;
      dst[j] = v ? d : -1;
      src[j] = s;
    }
#pragma unroll
    for (int j = 0; j < NE; ++j)
      if (dst[j] >= 0) pos[j] = atomicAdd(&cnt[dst[j]], 1);
#pragma unroll
    for (int j = 0; j < NE; ++j)
      if (dst[j] >= 0) csr[(dst[j] << 7) + pos[j]] = src[j];
    return;
  }
  // ---- gemm1: h1 = x @ W1, bf16 MFMA (global_load_lds staged), output bf16 ----
  __shared__ __align__(16) char smem[2 * BUFB];
  const int tid = threadIdx.x;
  const int lane = tid & 63;
  const int wid = tid >> 6;
  const int row0 = blockIdx.x * BM;
  const int wr = (wid >> 1) * 64;
  const int wc = (wid & 1) * 32;
  const int l15 = lane & 15, l4 = lane >> 4;

  const int lrq = tid >> 3;          // 0..31 (row within 32-row pass)
  const int mq = tid & 7;            // lds 16-B chunk slot
  const char* Xb = (const char*)X;
  size_t aoff[4];
#pragma unroll
  for (int q = 0; q < 4; ++q) {
    int lr = q * 32 + lrq;
    int gr = row0 + lr; if (gr >= NN) gr = NN - 1;
    int c = mq ^ (lr & 7);           // source chunk (inverse swizzle)
    aoff[q] = (size_t)gr * (FIN * 4) + (size_t)c * 16;
  }
  const unsigned short* bsrc =
      WT + (tid >> 2) * KPAD + (((tid & 3) ^ ((tid >> 3) & 3)) << 3);

  f32x4 acc[4][2];
#pragma unroll
  for (int a = 0; a < 4; ++a)
#pragma unroll
    for (int b = 0; b < 2; ++b) acc[a][b] = 0.f;

  auto gstage = [&](int k0, char* buf) {
#pragma unroll
    for (int q = 0; q < 4; ++q) {
      __builtin_amdgcn_global_load_lds(
          (u32_glb*)(Xb + aoff[q] + (size_t)k0 * 4),
          (u32_lds*)(buf + q * 4096 + wid * 1024), 16, 0, 0);
    }
  };

  gstage(0, smem);
  {
    short8 b0 = *(const short8*)(bsrc + 0);
    *(short8*)(smem + TILEA + tid * 16) = b0;
  }
  __syncthreads();

  int cur = 0;
  for (int t = 0; t < NT; ++t) {
    char* buf = smem + cur * BUFB;
    char* nbuf = smem + (cur ^ 1) * BUFB;
    const bool have_next = (t + 1 < NT);
    const bool tail = (t + 1 == NT - 1);
    short8 bnext;
    f32x4 atail[4];
    if (have_next) {
      if (!tail) {
        gstage((t + 1) * 32, nbuf);
      } else {
#pragma unroll
        for (int q = 0; q < 4; ++q) {
          int lr = q * 32 + lrq;
          int gr = row0 + lr; if (gr >= NN) gr = NN - 1;
          int c = mq ^ (lr & 7);
          int kb = (NT - 1) * 32 + c * 4;
          const float* xp = X + (size_t)gr * FIN + kb;
#pragma unroll
          for (int j = 0; j < 4; ++j)
            atail[q][j] = (kb + j < FIN) ? xp[j] : 0.f;
        }
      }
      bnext = *(const short8*)(bsrc + (t + 1) * 32);
    }

    short8 af[4], bf[2];
    const int sz = l15 & 7;
#pragma unroll
    for (int fr = 0; fr < 4; ++fr) {
      int r = wr + fr * 16 + l15;
      f32x4 a0 = *(const f32x4*)(buf + r * 128 + ((2 * l4) ^ sz) * 16);
      f32x4 a1 = *(const f32x4*)(buf + r * 128 + ((2 * l4 + 1) ^ sz) * 16);
      short8 v;
#pragma unroll
      for (int j = 0; j < 4; ++j) {
        v[j] = (short)f2bf(a0[j]);
        v[4 + j] = (short)f2bf(a1[j]);
      }
      af[fr] = v;
    }
#pragma unroll
    for (int fc = 0; fc < 2; ++fc) {
      int c = wc + fc * 16 + l15;
      int jp = l4 ^ ((c >> 1) & 3);
      bf[fc] = *(const short8*)(buf + TILEA + c * 64 + jp * 16);
    }
#pragma unroll
    for (int fr = 0; fr < 4; ++fr)
#pragma unroll
      for (int fc = 0; fc < 2; ++fc)
        acc[fr][fc] = __builtin_amdgcn_mfma_f32_16x16x32_bf16(
            af[fr], bf[fc], acc[fr][fc], 0, 0, 0);

    if (have_next) {
      if (tail) {
#pragma unroll
        for (int q = 0; q < 4; ++q)
          *(f32x4*)(nbuf + (q * 32 + lrq) * 128 + mq * 16) = atail[q];
      }
      *(short8*)(nbuf + TILEA + tid * 16) = bnext;
    }
    __syncthreads();
    cur ^= 1;
  }

  // epilogue: C/D layout col=lane&15, row=(lane>>4)*4+reg; store bf16
#pragma unroll
  for (int fr = 0; fr < 4; ++fr) {
    int rbase = row0 + wr + fr * 16 + l4 * 4;
#pragma unroll
    for (int q = 0; q < 4; ++q) {
      int r = rbase + q;
      if (r < NN) {
#pragma unroll
        for (int fc = 0; fc < 2; ++fc)
          Hb[(size_t)r * F1 + wc + fc * 16 + l15] = f2bf(acc[fr][fc][q]);
      }
    }
  }
}

// ---------------- per-node attention scores, layer 1 (8 threads/node) ----------------
__global__ __launch_bounds__(256) void k_att1(const unsigned short* __restrict__ Hb,
                                              const float* __restrict__ attS,
                                              const float* __restrict__ attD,
                                              float* __restrict__ aS,
                                              float* __restrict__ aD) {
  __shared__ float s_s[64], s_d[64];
  if (threadIdx.x < 64) { s_s[threadIdx.x] = attS[threadIdx.x]; s_d[threadIdx.x] = attD[threadIdx.x]; }
  __syncthreads();
  int idx = blockIdx.x * 256 + threadIdx.x;
  int n = idx >> 3, h = idx & 7;
  if (n >= NN) return;
  short8 v8 = *(const short8*)(Hb + (size_t)n * 64 + h * 8);
  float ss = 0.f, dd = 0.f;
#pragma unroll
  for (int c = 0; c < 8; ++c) {
    float v = bf2f((unsigned short)v8[c]);
    ss = fmaf(v, s_s[h * 8 + c], ss);
    dd = fmaf(v, s_d[h * 8 + c], dd);
  }
  aS[n * 8 + h] = ss;
  aD[n * 8 + h] = dd;
}

// ---------------- agg1 + fused gemm2/att2: wave per node, 8 edges x 8 heads ----
__global__ __launch_bounds__(256) void k_agg1(const unsigned short* __restrict__ Hb,
                                              const float* __restrict__ aS,
                                              const float* __restrict__ aD,
                                              const int* __restrict__ cnt,
                                              const int* __restrict__ csr,
                                              const float* __restrict__ b1,
                                              const float* __restrict__ W2,
                                              const float* __restrict__ s2,
                                              const float* __restrict__ d2,
                                              unsigned short* __restrict__ H2b,
                                              float* __restrict__ aD2) {
  __shared__ float s_w2[448];
  __shared__ float s_ss[7], s_dd[7];
  __shared__ float s_b1[64];
  for (int i = threadIdx.x; i < 448; i += 256) s_w2[i] = W2[i];
  if (threadIdx.x < 7) { s_ss[threadIdx.x] = s2[threadIdx.x]; s_dd[threadIdx.x] = d2[threadIdx.x]; }
  if (threadIdx.x < 64) s_b1[threadIdx.x] = b1[threadIdx.x];
  __syncthreads();

  const int wv = threadIdx.x >> 6, lane = threadIdx.x & 63;
  const int n = blockIdx.x * 4 + wv;
  if (n >= NN) return;
  const int eg = lane >> 3, q = lane & 7;
  const float adv = aD[n * 8 + q];
  const int beg = n << 7;
  const int deg = cnt[n];
  float acc[8] = {};
  float den = 0.f;
#pragma unroll 2
  for (int i = eg; i < deg; i += 8) {
    int s = csr[beg + i];                 // broadcast within eg-group
    float e = aS[s * 8 + q] + adv;
    e = (e > 0.f) ? e : 0.2f * e;         // leaky_relu
    float w = __expf(e);                  // max-shift unnecessary (|e| bounded)
    den += w;
    short8 hv = *(const short8*)(Hb + (size_t)s * 64 + q * 8);
#pragma unroll
    for (int c = 0; c < 8; ++c)
      acc[c] = fmaf(w, bf2f((unsigned short)hv[c]), acc[c]);
  }
#pragma unroll
  for (int off = 8; off < 64; off <<= 1) {
    den += __shfl_xor(den, off, 64);
#pragma unroll
    for (int c = 0; c < 8; ++c) acc[c] += __shfl_xor(acc[c], off, 64);
  }
  if (eg == 0) {                          // lanes 0..7: lane q holds head q's 8 ch
    float inv = 1.f / den;
    float v[8];
#pragma unroll
    for (int c = 0; c < 8; ++c) {
      float t = acc[c] * inv + s_b1[q * 8 + c];
      v[c] = (t > 0.f) ? t : (__expf(t) - 1.f);   // ELU
    }
    float p[7] = {};
#pragma unroll
    for (int c = 0; c < 8; ++c) {
      const float* wr = &s_w2[(q * 8 + c) * 7];
#pragma unroll
      for (int j = 0; j < 7; ++j) p[j] = fmaf(v[c], wr[j], p[j]);
    }
#pragma unroll
    for (int off = 1; off < 8; off <<= 1) {
#pragma unroll
      for (int j = 0; j < 7; ++j) p[j] += __shfl_xor(p[j], off, 64);
    }
    if (q == 0) {
      float s = 0.f, d = 0.f;
      short8 row;
#pragma unroll
      for (int j = 0; j < 7; ++j) {
        row[j] = (short)f2bf(p[j]);
        s = fmaf(p[j], s_ss[j], s);
        d = fmaf(p[j], s_dd[j], d);
      }
      row[7] = (short)f2bf(s);            // a_src score packed in slot 7
      *(short8*)(H2b + (size_t)n * 8) = row;
      aD2[n] = d;
    }
  }
}

// ---------------- aggregation layer 2: wave per node, lanes split edges ----------------
__global__ __launch_bounds__(256) void k_agg2(const unsigned short* __restrict__ H2b,
                                              const float* __restrict__ aD2,
                                              const int* __restrict__ cnt,
                                              const int* __restrict__ csr,
                                              const float* __restrict__ b2,
                                              float* __restrict__ out) {
  const int wv = threadIdx.x >> 6, lane = threadIdx.x & 63;
  const int n = blockIdx.x * 4 + wv;
  if (n >= NN) return;
  const float adv = aD2[n];
  const int beg = n << 7;
  const int deg = cnt[n];
  float acc[7] = {};
  float den = 0.f;
  for (int j = lane; j < deg; j += 64) {
    int s = csr[beg + j];
    short8 hv = *(const short8*)(H2b + (size_t)s * 8);
    float e = bf2f((unsigned short)hv[7]) + adv;
    e = (e > 0.f) ? e : 0.2f * e;
    float wgt = __expf(e);
    den += wgt;
#pragma unroll
    for (int c = 0; c < 7; ++c)
      acc[c] = fmaf(wgt, bf2f((unsigned short)hv[c]), acc[c]);
  }
#pragma unroll
  for (int off = 32; off > 0; off >>= 1) {
    den += __shfl_xor(den, off, 64);
#pragma unroll
    for (int c = 0; c < 7; ++c) acc[c] += __shfl_xor(acc[c], off, 64);
  }
  if (lane == 0) {
    float inv = 1.f / den;
    float v[7];
    float m = -1e30f;
#pragma unroll
    for (int c = 0; c < 7; ++c) { v[c] = acc[c] * inv + b2[c]; m = fmaxf(m, v[c]); }
    float se = 0.f;
#pragma unroll
    for (int c = 0; c < 7; ++c) se += __expf(v[c] - m);
    float lse = m + __logf(se);
#pragma unroll
    for (int c = 0; c < 7; ++c) out[n * 7 + c] = v[c] - lse;
  }
}

extern "C" void kernel_launch(void* const* d_in, const int* in_sizes, int n_in,
                              void* d_out, int out_size, void* d_ws, size_t ws_size,
                              hipStream_t stream) {
  const float* x   = (const float*)d_in[0];
  const int*   ei  = (const int*)d_in[1];
  const float* W1  = (const float*)d_in[2];
  const float* as1 = (const float*)d_in[3];
  const float* ad1 = (const float*)d_in[4];
  const float* b1  = (const float*)d_in[5];
  const float* W2  = (const float*)d_in[6];
  const float* as2 = (const float*)d_in[7];
  const float* ad2 = (const float*)d_in[8];
  const float* b2  = (const float*)d_in[9];
  float* out = (float*)d_out;

  char* ws = (char*)d_ws;
  size_t off = 0;
  auto alloc = [&](size_t bytes) {
    void* p = ws + off;
    off += (bytes + 255) & ~(size_t)255;
    return p;
  };
  unsigned short* h1b = (unsigned short*)alloc((size_t)NN * 64 * 2);
  float* sc1    = (float*)alloc((size_t)NN * 8 * 4);
  float* dc1    = (float*)alloc((size_t)NN * 8 * 4);
  unsigned short* h2b = (unsigned short*)alloc((size_t)NN * 8 * 2);
  float* dc2    = (float*)alloc((size_t)NN * 4);
  int*   cnt    = (int*)alloc((size_t)NN * 4);
  int*   csr    = (int*)alloc((size_t)NN * CAP * 4);
  unsigned short* w1t = (unsigned short*)alloc((size_t)F1 * KPAD * 2);

  // prep: zero cnt + W1^T
  k_prep<<<NB, 256, 0, stream>>>(W1, cnt, w1t);

  // gemm1 || batched scatter
  k_fuse1<<<G1B + SB, 256, 0, stream>>>(x, w1t, h1b, ei, cnt, csr);

  // attention scores layer 1
  k_att1<<<(NN * 8 + 255) / 256, 256, 0, stream>>>(h1b, as1, ad1, sc1, dc1);

  // agg1 + fused gemm2/att2
  k_agg1<<<(NN + 3) / 4, 256, 0, stream>>>(h1b, sc1, dc1, cnt, csr, b1,
                                           W2, as2, ad2, h2b, dc2);

  // agg2 + log_softmax
  k_agg2<<<(NN + 3) / 4, 256, 0, stream>>>(h2b, dc2, cnt, csr, b2, out);
}

// Round 14
// 436.809 us; speedup vs baseline: 1.1050x; 1.0178x over previous
//
#include <hip/hip_runtime.h>
#include <hip/hip_bf16.h>
#include <math.h>

#define NN 100000
#define EE 3200000
#define ET (EE + NN)          // edges incl. self loops
#define FIN 1433
#define KPAD 1440
#define NT 45                 // K tiles of 32
#define F1 64
#define F2 7
#define G1B 782               // gemm1 blocks (ceil(NN/BM))
#define CAP 128               // padded CSR capacity per node
#define BINS 200              // dst>>9 -> 0..195 (padded)
#define SB1 256               // binning blocks
#define CH_E 12891            // ceil(ET/SB1)
#define NB4 196               // bucket-group blocks ((NN+511)>>9)
#define A1B 3125              // att1 blocks (NN*8/256)

typedef __attribute__((ext_vector_type(8))) short short8;
typedef __attribute__((ext_vector_type(4))) float f32x4;
typedef __attribute__((address_space(3))) unsigned int u32_lds;
typedef __attribute__((address_space(1))) const unsigned int u32_glb;

static __device__ __forceinline__ unsigned short f2bf(float f) {
  __hip_bfloat16 h = __float2bfloat16(f);
  return *reinterpret_cast<unsigned short*>(&h);
}
static __device__ __forceinline__ float bf2f(unsigned short u) {
  return __uint_as_float((unsigned int)u << 16);
}

// ---------------- prep: W1^T bf16 (padded) ----------------
__global__ __launch_bounds__(256) void k_prep(const float* __restrict__ W1,
                                              unsigned short* __restrict__ WT) {
  int i = blockIdx.x * 256 + threadIdx.x;
  if (i < F1 * KPAD) {
    int c = i / KPAD, k = i - c * KPAD;
    WT[i] = f2bf((k < FIN) ? W1[k * F1 + c] : 0.f);
  }
}

// ---------------- fuse1: gemm1 (blocks 0..G1B) || B1 bucket histogram ----------------
#define BM 128
#define TILEA 16384           // 128 rows x 32 k x f32
#define TILEB 4096            // 64 cols x 32 k x bf16
#define BUFB (TILEA + TILEB)  // 20480

__global__ __launch_bounds__(256) void k_fuse1(const float* __restrict__ X,
                                               const unsigned short* __restrict__ WT,
                                               unsigned short* __restrict__ Hb,
                                               const int* __restrict__ ei,
                                               int* __restrict__ histM) {
  if (blockIdx.x >= G1B) {
    // ---- B1: per-block LDS histogram of dst buckets (LDS atomics only) ----
    __shared__ int hist[BINS];
    const int b = blockIdx.x - G1B;
    for (int i = threadIdx.x; i < BINS; i += 256) hist[i] = 0;
    __syncthreads();
    const int e0 = b * CH_E, e1 = min(e0 + CH_E, ET);
    for (int e = e0 + threadIdx.x; e < e1; e += 256) {
      int dst = (e < EE) ? ei[EE + e] : (e - EE);
      atomicAdd(&hist[dst >> 9], 1);
    }
    __syncthreads();
    for (int i = threadIdx.x; i < BINS; i += 256) histM[b * BINS + i] = hist[i];
    return;
  }
  // ---- gemm1: h1 = x @ W1, bf16 MFMA (global_load_lds staged), output bf16 ----
  __shared__ __align__(16) char smem[2 * BUFB];
  const int tid = threadIdx.x;
  const int lane = tid & 63;
  const int wid = tid >> 6;
  const int row0 = blockIdx.x * BM;
  const int wr = (wid >> 1) * 64;
  const int wc = (wid & 1) * 32;
  const int l15 = lane & 15, l4 = lane >> 4;

  const int lrq = tid >> 3;          // 0..31 (row within 32-row pass)
  const int mq = tid & 7;            // lds 16-B chunk slot
  const char* Xb = (const char*)X;
  size_t aoff[4];
#pragma unroll
  for (int q = 0; q < 4; ++q) {
    int lr = q * 32 + lrq;
    int gr = row0 + lr; if (gr >= NN) gr = NN - 1;
    int c = mq ^ (lr & 7);           // source chunk (inverse swizzle)
    aoff[q] = (size_t)gr * (FIN * 4) + (size_t)c * 16;
  }
  const unsigned short* bsrc =
      WT + (tid >> 2) * KPAD + (((tid & 3) ^ ((tid >> 3) & 3)) << 3);

  f32x4 acc[4][2];
#pragma unroll
  for (int a = 0; a < 4; ++a)
#pragma unroll
    for (int b = 0; b < 2; ++b) acc[a][b] = 0.f;

  auto gstage = [&](int k0, char* buf) {
#pragma unroll
    for (int q = 0; q < 4; ++q) {
      __builtin_amdgcn_global_load_lds(
          (u32_glb*)(Xb + aoff[q] + (size_t)k0 * 4),
          (u32_lds*)(buf + q * 4096 + wid * 1024), 16, 0, 0);
    }
  };

  gstage(0, smem);
  {
    short8 b0 = *(const short8*)(bsrc + 0);
    *(short8*)(smem + TILEA + tid * 16) = b0;
  }
  __syncthreads();

  int cur = 0;
  for (int t = 0; t < NT; ++t) {
    char* buf = smem + cur * BUFB;
    char* nbuf = smem + (cur ^ 1) * BUFB;
    const bool have_next = (t + 1 < NT);
    const bool tail = (t + 1 == NT - 1);
    short8 bnext;
    f32x4 atail[4];
    if (have_next) {
      if (!tail) {
        gstage((t + 1) * 32, nbuf);
      } else {
#pragma unroll
        for (int q = 0; q < 4; ++q) {
          int lr = q * 32 + lrq;
          int gr = row0 + lr; if (gr >= NN) gr = NN - 1;
          int c = mq ^ (lr & 7);
          int kb = (NT - 1) * 32 + c * 4;
          const float* xp = X + (size_t)gr * FIN + kb;
#pragma unroll
          for (int j = 0; j < 4; ++j)
            atail[q][j] = (kb + j < FIN) ? xp[j] : 0.f;
        }
      }
      bnext = *(const short8*)(bsrc + (t + 1) * 32);
    }

    short8 af[4], bf[2];
    const int sz = l15 & 7;
#pragma unroll
    for (int fr = 0; fr < 4; ++fr) {
      int r = wr + fr * 16 + l15;
      f32x4 a0 = *(const f32x4*)(buf + r * 128 + ((2 * l4) ^ sz) * 16);
      f32x4 a1 = *(const f32x4*)(buf + r * 128 + ((2 * l4 + 1) ^ sz) * 16);
      short8 v;
#pragma unroll
      for (int j = 0; j < 4; ++j) {
        v[j] = (short)f2bf(a0[j]);
        v[4 + j] = (short)f2bf(a1[j]);
      }
      af[fr] = v;
    }
#pragma unroll
    for (int fc = 0; fc < 2; ++fc) {
      int c = wc + fc * 16 + l15;
      int jp = l4 ^ ((c >> 1) & 3);
      bf[fc] = *(const short8*)(buf + TILEA + c * 64 + jp * 16);
    }
#pragma unroll
    for (int fr = 0; fr < 4; ++fr)
#pragma unroll
      for (int fc = 0; fc < 2; ++fc)
        acc[fr][fc] = __builtin_amdgcn_mfma_f32_16x16x32_bf16(
            af[fr], bf[fc], acc[fr][fc], 0, 0, 0);

    if (have_next) {
      if (tail) {
#pragma unroll
        for (int q = 0; q < 4; ++q)
          *(f32x4*)(nbuf + (q * 32 + lrq) * 128 + mq * 16) = atail[q];
      }
      *(short8*)(nbuf + TILEA + tid * 16) = bnext;
    }
    __syncthreads();
    cur ^= 1;
  }

  // epilogue: C/D layout col=lane&15, row=(lane>>4)*4+reg; store bf16
#pragma unroll
  for (int fr = 0; fr < 4; ++fr) {
    int rbase = row0 + wr + fr * 16 + l4 * 4;
#pragma unroll
    for (int q = 0; q < 4; ++q) {
      int r = rbase + q;
      if (r < NN) {
#pragma unroll
        for (int fc = 0; fc < 2; ++fc)
          Hb[(size_t)r * F1 + wc + fc * 16 + l15] = f2bf(acc[fr][fc][q]);
      }
    }
  }
}

// ---------------- B2: scan histM -> exact per-(block,bin) offsets ----------------
__global__ __launch_bounds__(256) void k_scanM(int* __restrict__ histM,
                                               int* __restrict__ binS,
                                               int* __restrict__ binE) {
  __shared__ int s[256];
  const int t = threadIdx.x;
  int total = 0;
  if (t < BINS)
    for (int b = 0; b < SB1; ++b) total += histM[b * BINS + t];
  s[t] = total;
  __syncthreads();
  for (int off = 1; off < 256; off <<= 1) {
    int v = s[t];
    int u = (t >= off) ? s[t - off] : 0;
    __syncthreads();
    s[t] = v + u;
    __syncthreads();
  }
  if (t < BINS) {
    int run = s[t] - total;            // exclusive prefix
    binS[t] = run;
    for (int b = 0; b < SB1; ++b) {
      int h = histM[b * BINS + t];
      histM[b * BINS + t] = run;
      run += h;
    }
    binE[t] = run;
  }
}

// ---------------- B3: bin edges (plain stores, no global atomics) ----------------
__global__ __launch_bounds__(256) void k_bin(const int* __restrict__ ei,
                                             const int* __restrict__ histM,
                                             unsigned int* __restrict__ binned) {
  __shared__ int cur[BINS];
  const int b = blockIdx.x;
  for (int i = threadIdx.x; i < BINS; i += 256) cur[i] = histM[b * BINS + i];
  __syncthreads();
  const int e0 = b * CH_E, e1 = min(e0 + CH_E, ET);
  for (int e = e0 + threadIdx.x; e < e1; e += 256) {
    int dst = (e < EE) ? ei[EE + e] : (e - EE);
    int src = (e < EE) ? ei[e] : dst;
    int pos = atomicAdd(&cur[dst >> 9], 1);        // LDS atomic
    binned[pos] = ((unsigned)(dst & 511) << 17) | (unsigned)src;
  }
}

// ---------------- fuse2: att1 (blocks 0..A1B) || B4 bucket-group ----------------
__global__ __launch_bounds__(256) void k_fuse2(const unsigned short* __restrict__ Hb,
                                               const float* __restrict__ attS,
                                               const float* __restrict__ attD,
                                               float* __restrict__ aS,
                                               float* __restrict__ aD,
                                               const unsigned int* __restrict__ binned,
                                               const int* __restrict__ binS,
                                               const int* __restrict__ binE,
                                               int* __restrict__ cnt,
                                               int* __restrict__ csr) {
  if (blockIdx.x >= A1B) {
    // ---- B4: group one bucket's edges into padded CSR (LDS atomics only) ----
    __shared__ int lcnt[512];
    const int g = blockIdx.x - A1B;
    for (int i = threadIdx.x; i < 512; i += 256) lcnt[i] = 0;
    __syncthreads();
    const int s0 = binS[g], s1 = binE[g];
    const int nbase = g << 9;
    for (int i = s0 + threadIdx.x; i < s1; i += 256) {
      unsigned v = binned[i];
      int ld = v >> 17;
      int src = (int)(v & 0x1FFFFu);
      int pos = atomicAdd(&lcnt[ld], 1);           // LDS atomic
      csr[((size_t)(nbase + ld) << 7) + pos] = src;
    }
    __syncthreads();
    for (int i = threadIdx.x; i < 512; i += 256) {
      int n = nbase + i;
      if (n < NN) cnt[n] = lcnt[i];
    }
    return;
  }
  // ---- att1: per-node attention scores (8 threads/node) ----
  __shared__ float s_s[64], s_d[64];
  if (threadIdx.x < 64) { s_s[threadIdx.x] = attS[threadIdx.x]; s_d[threadIdx.x] = attD[threadIdx.x]; }
  __syncthreads();
  int idx = blockIdx.x * 256 + threadIdx.x;
  int n = idx >> 3, h = idx & 7;
  if (n >= NN) return;
  short8 v8 = *(const short8*)(Hb + (size_t)n * 64 + h * 8);
  float ss = 0.f, dd = 0.f;
#pragma unroll
  for (int c = 0; c < 8; ++c) {
    float v = bf2f((unsigned short)v8[c]);
    ss = fmaf(v, s_s[h * 8 + c], ss);
    dd = fmaf(v, s_d[h * 8 + c], dd);
  }
  aS[n * 8 + h] = ss;
  aD[n * 8 + h] = dd;
}

// ---------------- agg1 + fused gemm2/att2: wave per node, 8 edges x 8 heads ----
__global__ __launch_bounds__(256) void k_agg1(const unsigned short* __restrict__ Hb,
                                              const float* __restrict__ aS,
                                              const float* __restrict__ aD,
                                              const int* __restrict__ cnt,
                                              const int* __restrict__ csr,
                                              const float* __restrict__ b1,
                                              const float* __restrict__ W2,
                                              const float* __restrict__ s2,
                                              const float* __restrict__ d2,
                                              unsigned short* __restrict__ H2b,
                                              float* __restrict__ aD2) {
  __shared__ float s_w2[448];
  __shared__ float s_ss[7], s_dd[7];
  __shared__ float s_b1[64];
  for (int i = threadIdx.x; i < 448; i += 256) s_w2[i] = W2[i];
  if (threadIdx.x < 7) { s_ss[threadIdx.x] = s2[threadIdx.x]; s_dd[threadIdx.x] = d2[threadIdx.x]; }
  if (threadIdx.x < 64) s_b1[threadIdx.x] = b1[threadIdx.x];
  __syncthreads();

  const int wv = threadIdx.x >> 6, lane = threadIdx.x & 63;
  const int n = blockIdx.x * 4 + wv;
  if (n >= NN) return;
  const int eg = lane >> 3, q = lane & 7;
  const float adv = aD[n * 8 + q];
  const int beg = n << 7;
  const int deg = cnt[n];
  float acc[8] = {};
  float den = 0.f;
#pragma unroll 2
  for (int i = eg; i < deg; i += 8) {
    int s = csr[beg + i];                 // broadcast within eg-group
    float e = aS[s * 8 + q] + adv;
    e = (e > 0.f) ? e : 0.2f * e;         // leaky_relu
    float w = __expf(e);                  // max-shift unnecessary (|e| bounded)
    den += w;
    short8 hv = *(const short8*)(Hb + (size_t)s * 64 + q * 8);
#pragma unroll
    for (int c = 0; c < 8; ++c)
      acc[c] = fmaf(w, bf2f((unsigned short)hv[c]), acc[c]);
  }
#pragma unroll
  for (int off = 8; off < 64; off <<= 1) {
    den += __shfl_xor(den, off, 64);
#pragma unroll
    for (int c = 0; c < 8; ++c) acc[c] += __shfl_xor(acc[c], off, 64);
  }
  if (eg == 0) {                          // lanes 0..7: lane q holds head q's 8 ch
    float inv = 1.f / den;
    float v[8];
#pragma unroll
    for (int c = 0; c < 8; ++c) {
      float t = acc[c] * inv + s_b1[q * 8 + c];
      v[c] = (t > 0.f) ? t : (__expf(t) - 1.f);   // ELU
    }
    float p[7] = {};
#pragma unroll
    for (int c = 0; c < 8; ++c) {
      const float* wr = &s_w2[(q * 8 + c) * 7];
#pragma unroll
      for (int j = 0; j < 7; ++j) p[j] = fmaf(v[c], wr[j], p[j]);
    }
#pragma unroll
    for (int off = 1; off < 8; off <<= 1) {
#pragma unroll
      for (int j = 0; j < 7; ++j) p[j] += __shfl_xor(p[j], off, 64);
    }
    if (q == 0) {
      float s = 0.f, d = 0.f;
      short8 row;
#pragma unroll
      for (int j = 0; j < 7; ++j) {
        row[j] = (short)f2bf(p[j]);
        s = fmaf(p[j], s_ss[j], s);
        d = fmaf(p[j], s_dd[j], d);
      }
      row[7] = (short)f2bf(s);            // a_src score packed in slot 7
      *(short8*)(H2b + (size_t)n * 8) = row;
      aD2[n] = d;
    }
  }
}

// ---------------- aggregation layer 2: wave per node, lanes split edges ----------------
__global__ __launch_bounds__(256) void k_agg2(const unsigned short* __restrict__ H2b,
                                              const float* __restrict__ aD2,
                                              const int* __restrict__ cnt,
                                              const int* __restrict__ csr,
                                              const float* __restrict__ b2,
                                              float* __restrict__ out) {
  const int wv = threadIdx.x >> 6, lane = threadIdx.x & 63;
  const int n = blockIdx.x * 4 + wv;
  if (n >= NN) return;
  const float adv = aD2[n];
  const int beg = n << 7;
  const int deg = cnt[n];
  float acc[7] = {};
  float den = 0.f;
  for (int j = lane; j < deg; j += 64) {
    int s = csr[beg + j];
    short8 hv = *(const short8*)(H2b + (size_t)s * 8);
    float e = bf2f((unsigned short)hv[7]) + adv;
    e = (e > 0.f) ? e : 0.2f * e;
    float wgt = __expf(e);
    den += wgt;
#pragma unroll
    for (int c = 0; c < 7; ++c)
      acc[c] = fmaf(wgt, bf2f((unsigned short)hv[c]), acc[c]);
  }
#pragma unroll
  for (int off = 32; off > 0; off >>= 1) {
    den += __shfl_xor(den, off, 64);
#pragma unroll
    for (int c = 0; c < 7; ++c) acc[c] += __shfl_xor(acc[c], off, 64);
  }
  if (lane == 0) {
    float inv = 1.f / den;
    float v[7];
    float m = -1e30f;
#pragma unroll
    for (int c = 0; c < 7; ++c) { v[c] = acc[c] * inv + b2[c]; m = fmaxf(m, v[c]); }
    float se = 0.f;
#pragma unroll
    for (int c = 0; c < 7; ++c) se += __expf(v[c] - m);
    float lse = m + __logf(se);
#pragma unroll
    for (int c = 0; c < 7; ++c) out[n * 7 + c] = v[c] - lse;
  }
}

extern "C" void kernel_launch(void* const* d_in, const int* in_sizes, int n_in,
                              void* d_out, int out_size, void* d_ws, size_t ws_size,
                              hipStream_t stream) {
  const float* x   = (const float*)d_in[0];
  const int*   ei  = (const int*)d_in[1];
  const float* W1  = (const float*)d_in[2];
  const float* as1 = (const float*)d_in[3];
  const float* ad1 = (const float*)d_in[4];
  const float* b1  = (const float*)d_in[5];
  const float* W2  = (const float*)d_in[6];
  const float* as2 = (const float*)d_in[7];
  const float* ad2 = (const float*)d_in[8];
  const float* b2  = (const float*)d_in[9];
  float* out = (float*)d_out;

  char* ws = (char*)d_ws;
  size_t off = 0;
  auto alloc = [&](size_t bytes) {
    void* p = ws + off;
    off += (bytes + 255) & ~(size_t)255;
    return p;
  };
  unsigned short* h1b = (unsigned short*)alloc((size_t)NN * 64 * 2);
  float* sc1    = (float*)alloc((size_t)NN * 8 * 4);
  float* dc1    = (float*)alloc((size_t)NN * 8 * 4);
  unsigned short* h2b = (unsigned short*)alloc((size_t)NN * 8 * 2);
  float* dc2    = (float*)alloc((size_t)NN * 4);
  int*   cnt    = (int*)alloc((size_t)NN * 4);
  int*   csr    = (int*)alloc((size_t)NN * CAP * 4);
  int*   histM  = (int*)alloc((size_t)SB1 * BINS * 4);
  int*   binS   = (int*)alloc((size_t)BINS * 4);
  int*   binE   = (int*)alloc((size_t)BINS * 4);
  unsigned int* binned = (unsigned int*)alloc((size_t)ET * 4);
  unsigned short* w1t = (unsigned short*)alloc((size_t)F1 * KPAD * 2);

  // prep: W1^T
  k_prep<<<(F1 * KPAD + 255) / 256, 256, 0, stream>>>(W1, w1t);

  // gemm1 || B1 bucket histogram
  k_fuse1<<<G1B + SB1, 256, 0, stream>>>(x, w1t, h1b, ei, histM);

  // B2: offsets
  k_scanM<<<1, 256, 0, stream>>>(histM, binS, binE);

  // B3: bin edges (no global atomics)
  k_bin<<<SB1, 256, 0, stream>>>(ei, histM, binned);

  // att1 || B4 bucket-group -> padded CSR
  k_fuse2<<<A1B + NB4, 256, 0, stream>>>(h1b, as1, ad1, sc1, dc1,
                                         binned, binS, binE, cnt, csr);

  // agg1 + fused gemm2/att2
  k_agg1<<<(NN + 3) / 4, 256, 0, stream>>>(h1b, sc1, dc1, cnt, csr, b1,
                                           W2, as2, ad2, h2b, dc2);

  // agg2 + log_softmax
  k_agg2<<<(NN + 3) / 4, 256, 0, stream>>>(h2b, dc2, cnt, csr, b2, out);
}